// Round 7
// baseline (4794.094 us; speedup 1.0000x reference)
//
#include <hip/hip_runtime.h>
#include <math.h>

#define IN_DIM 8192
#define HID 128
#define NSTEPS 4096

typedef _Float16 f16x2 __attribute__((ext_vector_type(2)));
union F4H8 { float4 f4; f16x2 h[4]; };

__device__ __forceinline__ f16x2 cvt2(float2 p) {
    f16x2 r; r.x = (_Float16)p.x; r.y = (_Float16)p.y; return r;
}
__device__ __forceinline__ float sigm(float x) { return 1.f / (1.f + __expf(-x)); }
__device__ __forceinline__ float tanh_f(float x) {
    x = fminf(fmaxf(x, -15.f), 15.f);          // avoid inf/inf NaN
    float e = __expf(2.f * x);
    return (e - 1.f) / (e + 1.f);
}
// quad (lanes 4k..4k+3) all-sum via DPP quad_perm — VALU pipe, keeps the DS
// pipe free (__shfl_xor may lower to ds_swizzle on CDNA).
__device__ __forceinline__ float qsum4(float a) {
    int y = __builtin_amdgcn_update_dpp(0, __float_as_int(a), 0xB1, 0xF, 0xF, true); // xor 1
    a += __int_as_float(y);
    y = __builtin_amdgcn_update_dpp(0, __float_as_int(a), 0x4E, 0xF, 0xF, true);     // xor 2
    a += __int_as_float(y);
    return a;
}

// ---------------------------------------------------------------------------
// Kernel 1: M = W_enc @ W_dec  (128x128), cvec = W_enc@b_dec + b_enc,
//           e1 = W_enc@x0 + b_enc.  Grid: 128 blocks (one per row p), 128 thr.
// ---------------------------------------------------------------------------
__global__ __launch_bounds__(128) void k_precompute_M(
    const float* __restrict__ W_enc, const float* __restrict__ W_dec,
    const float* __restrict__ b_enc, const float* __restrict__ b_dec,
    const float* __restrict__ x0,
    float* __restrict__ M, float* __restrict__ cvec, float* __restrict__ e1)
{
    const int p = blockIdx.x;
    const int t = threadIdx.x;              // 0..127 (= output column q)
    __shared__ float wl[128];
    __shared__ float red[256];
    float m0 = 0.f, m1 = 0.f, m2 = 0.f, m3 = 0.f, cacc = 0.f, eacc = 0.f;
    for (int i0 = 0; i0 < IN_DIM; i0 += 128) {
        float w = W_enc[(size_t)p * IN_DIM + i0 + t];   // coalesced
        cacc = fmaf(w, b_dec[i0 + t], cacc);
        eacc = fmaf(w, x0[i0 + t], eacc);
        wl[t] = w;
        __syncthreads();
#pragma unroll 8
        for (int k = 0; k < 128; k += 4) {              // W_dec reads coalesced in t
            m0 = fmaf(wl[k],     W_dec[(size_t)(i0 + k) * HID + t], m0);
            m1 = fmaf(wl[k + 1], W_dec[(size_t)(i0 + k + 1) * HID + t], m1);
            m2 = fmaf(wl[k + 2], W_dec[(size_t)(i0 + k + 2) * HID + t], m2);
            m3 = fmaf(wl[k + 3], W_dec[(size_t)(i0 + k + 3) * HID + t], m3);
        }
        __syncthreads();
    }
    M[p * HID + t] = (m0 + m1) + (m2 + m3);
    red[t] = cacc; red[128 + t] = eacc;
    __syncthreads();
    for (int s = 64; s > 0; s >>= 1) {
        if (t < s) { red[t] += red[t + s]; red[128 + t] += red[128 + t + s]; }
        __syncthreads();
    }
    if (t == 0) { cvec[p] = red[0] + b_enc[p]; e1[p] = red[128] + b_enc[p]; }
}

// ---------------------------------------------------------------------------
// Kernel 2: G rows 0..383 = W_ih@M, rows 384..767 = W_hh (copy).
//           gb[0..383] = W_ih@cvec + bias, gb[384..767] = 0.
//           ig1 = W_ih@e1 + bias.  Grid: 768 blocks, 128 threads.
// ---------------------------------------------------------------------------
__global__ __launch_bounds__(128) void k_precompute_G(
    const float* __restrict__ W_ih, const float* __restrict__ W_hh,
    const float* __restrict__ bias, const float* __restrict__ M,
    const float* __restrict__ cvec, const float* __restrict__ e1,
    float* __restrict__ G, float* __restrict__ gb, float* __restrict__ ig1)
{
    const int r = blockIdx.x;
    const int q = threadIdx.x;
    if (r >= 384) {
        G[(size_t)r * HID + q] = W_hh[(size_t)(r - 384) * HID + q];
        if (q == 0) gb[r] = 0.f;
        return;
    }
    __shared__ float red[256];
    float a0 = 0.f, a1 = 0.f, a2 = 0.f, a3 = 0.f;
#pragma unroll 8
    for (int k = 0; k < HID; k += 4) {   // W_ih[r][k] scalar-uniform, M coalesced
        a0 = fmaf(W_ih[r * HID + k],     M[(k) * HID + q], a0);
        a1 = fmaf(W_ih[r * HID + k + 1], M[(k + 1) * HID + q], a1);
        a2 = fmaf(W_ih[r * HID + k + 2], M[(k + 2) * HID + q], a2);
        a3 = fmaf(W_ih[r * HID + k + 3], M[(k + 3) * HID + q], a3);
    }
    G[(size_t)r * HID + q] = (a0 + a1) + (a2 + a3);
    float wq = W_ih[r * HID + q];
    red[q] = wq * cvec[q];
    red[128 + q] = wq * e1[q];
    __syncthreads();
    for (int s = 64; s > 0; s >>= 1) {
        if (q < s) { red[q] += red[q + s]; red[128 + q] += red[128 + q + s]; }
        __syncthreads();
    }
    if (q == 0) { gb[r] = red[0] + bias[r]; ig1[r] = red[128] + bias[r]; }
}

// ---------------------------------------------------------------------------
// Kernel 3: sequential GRU scan. ONE block, 1024 threads (16 waves, 4/SIMD).
// R1-R6 lesson: "+v"-pinned weight masses ALWAYS lose to the allocator's
// occupancy heuristic (VGPR stuck at 40-84, weights in scratch). New
// mechanism: weights live in AGPRs (gfx950 unified file, separate allocation
// class with zero VGPR pressure); every use is an explicit
// v_accvgpr_read_b32 with an "a" input constraint, so residence is the only
// cheap allocation (HK precedent: AGPR accumulators persist across K-loops).
// Thread t: K-quarter q=t&3 of rows r0, r0+256, r0+512 (r0=t>>2) as 48 f16x2
// AGPRs. f16 weights validated R6: absmax identical to f32. gb/bias_n moved
// to LDS to shave loop-carried VGPRs; quad-reduce via DPP (VALU pipe).
// ---------------------------------------------------------------------------
#define K16(F) F(0) F(1) F(2) F(3) F(4) F(5) F(6) F(7) F(8) F(9) F(10) F(11) \
    F(12) F(13) F(14) F(15)

#define RD(d, s) asm volatile("v_accvgpr_read_b32 %0, %1" : "=v"(d) : "a"(s));

__global__ __launch_bounds__(1024, 4) void k_recurrence(
    const float* __restrict__ G, const float* __restrict__ gb,
    const float* __restrict__ ig1, const float* __restrict__ bias_n,
    float* __restrict__ H)
{
    const int t  = threadIdx.x;          // 0..1023
    const int q  = t & 3;                // K-quarter: k in [32q, 32q+32)
    const int r0 = t >> 2;               // 0..255; rows r0, r0+256, r0+512
    __shared__ _Float16 h_rep[4 * 144];  // 4 replicas, stride 144 f16 = 288 B
    __shared__ float h_f32[HID];         // full-precision h for gate math
    __shared__ float g_lds[6 * HID];     // 768
    __shared__ float gb_lds[6 * HID];    // 768 folded bias
    __shared__ float bn_lds[HID];

    if (t < 6 * HID) gb_lds[t] = gb[t];
    if (t < HID)     bn_lds[t] = bias_n[t];

    const float2* gp0 = (const float2*)(G + (size_t)(r0)       * HID + 32 * q);
    const float2* gp1 = (const float2*)(G + (size_t)(r0 + 256) * HID + 32 * q);
    const float2* gp2 = (const float2*)(G + (size_t)(r0 + 512) * HID + 32 * q);
#define DECL_W(i) f16x2 w0_##i = cvt2(gp0[i]); f16x2 w1_##i = cvt2(gp1[i]); \
                  f16x2 w2_##i = cvt2(gp2[i]);
    K16(DECL_W)
#undef DECL_W
    // Place all 48 weight values into AGPRs now (one-time accvgpr_writes).
#define PIN_A(i) asm volatile("" : "+a"(w0_##i), "+a"(w1_##i), "+a"(w2_##i));
    K16(PIN_A)
#undef PIN_A

    // step 1: h0 = 0 => hg = 0, use precomputed ig1
    if (t < HID) {
        float ir = ig1[t], iz = ig1[HID + t], inn = ig1[2 * HID + t];
        float rg = sigm(ir), zg = sigm(iz);
        float ng = tanh_f(fmaf(rg, bn_lds[t], inn));
        float h1 = ng - zg * ng;            // n + z*(0 - n)
        _Float16 h16 = (_Float16)h1;
        h_f32[t] = h1;
        h_rep[t] = h16; h_rep[144 + t] = h16;
        h_rep[288 + t] = h16; h_rep[432 + t] = h16;
        H[t] = h1;
    }
    __syncthreads();

    // replica q base = 288q B; K-quarter byte offset = 64q B -> 352q B total
    const float4* hq4 = (const float4*)((const char*)h_rep + 352 * q);
    for (int st = 1; st < NSTEPS; ++st) {
        float a0 = 0.f, a1 = 0.f, a2 = 0.f;
        // Per chunk: 12 accvgpr_reads then 12 dot2s (read->use distance
        // covers VALU latency; accumulator dep distance = 3).
#define DOT1(idx, hp) { f16x2 t0v, t1v, t2v; \
        RD(t0v, w0_##idx) RD(t1v, w1_##idx) RD(t2v, w2_##idx) \
        a0 = __builtin_amdgcn_fdot2(t0v, hp, a0, false); \
        a1 = __builtin_amdgcn_fdot2(t1v, hp, a1, false); \
        a2 = __builtin_amdgcn_fdot2(t2v, hp, a2, false); }
#define DOTB(j, iA, iB, iC, iD) { F4H8 u; u.f4 = hq4[j]; \
        DOT1(iA, u.h[0]) DOT1(iB, u.h[1]) DOT1(iC, u.h[2]) DOT1(iD, u.h[3]) }
        DOTB(0, 0, 1, 2, 3)
        DOTB(1, 4, 5, 6, 7)
        DOTB(2, 8, 9, 10, 11)
        DOTB(3, 12, 13, 14, 15)
#undef DOTB
#undef DOT1
        // intra-quad all-sum (DPP, VALU pipe)
        a0 = qsum4(a0); a1 = qsum4(a1); a2 = qsum4(a2);
        if (q == 0) {
            g_lds[r0]       = a0 + gb_lds[r0];
            g_lds[r0 + 256] = a1 + gb_lds[r0 + 256];
            g_lds[r0 + 512] = a2 + gb_lds[r0 + 512];
        }
        __syncthreads();
        if (t < HID) {                      // waves 0,1 only; uniform branch
            float ir = g_lds[t],           iz = g_lds[HID + t],     inn = g_lds[2 * HID + t];
            float hr = g_lds[3 * HID + t], hz = g_lds[4 * HID + t], hn = g_lds[5 * HID + t];
            float rg = sigm(ir + hr);
            float zg = sigm(iz + hz);
            float ng = tanh_f(inn + rg * (hn + bn_lds[t]));
            float hp = h_f32[t];
            float hnew = ng + zg * (hp - ng);
            _Float16 h16 = (_Float16)hnew;
            h_f32[t] = hnew;
            h_rep[t] = h16; h_rep[144 + t] = h16;
            h_rep[288 + t] = h16; h_rep[432 + t] = h16;
            H[(size_t)st * HID + t] = hnew;
        }
        __syncthreads();
    }
}

// ---------------------------------------------------------------------------
// Kernel 4: out[t][i] = dot(H[t][:], W_dec[i][:]) + b_dec[i]
// GEMM M=4096(t) N=8192(i) K=128, fp32 vector. 64x64 tiles, 256 threads,
// 4x4 micro-tile (strided by 16), XOR-swizzled LDS (64KB total, conflict-free).
// ---------------------------------------------------------------------------
__global__ __launch_bounds__(256) void k_decode(
    const float* __restrict__ H, const float* __restrict__ W_dec,
    const float* __restrict__ b_dec, float* __restrict__ out)
{
    __shared__ float4 As[64 * 32];   // [t][k4], k4 XOR-swizzled by (t&7)
    __shared__ float4 Bs[64 * 32];   // [i][k4]
    const int tid = threadIdx.x;
    const int t0 = blockIdx.y * 64;
    const int i0 = blockIdx.x * 64;
#pragma unroll 8
    for (int j = 0; j < 8; ++j) {
        int f = tid + 256 * j;        // 0..2047 float4s, coalesced
        int t = f >> 5;
        int k4 = f & 31;
        int sw = k4 ^ (t & 7);
        As[t * 32 + sw] = *(const float4*)(H + (size_t)(t0 + t) * HID + 4 * k4);
        Bs[t * 32 + sw] = *(const float4*)(W_dec + (size_t)(i0 + t) * HID + 4 * k4);
    }
    __syncthreads();
    const int tx = tid & 15, ty = tid >> 4;
    const int xa = ty & 7, xb = tx & 7;
    float acc[4][4] = {{0.f}};
#pragma unroll 8
    for (int k4 = 0; k4 < 32; ++k4) {
        float4 a[4], b[4];
        int ia = k4 ^ xa, ib = k4 ^ xb;
#pragma unroll
        for (int u = 0; u < 4; ++u) a[u] = As[(ty + 16 * u) * 32 + ia];
#pragma unroll
        for (int v = 0; v < 4; ++v) b[v] = Bs[(tx + 16 * v) * 32 + ib];
#pragma unroll
        for (int u = 0; u < 4; ++u)
#pragma unroll
            for (int v = 0; v < 4; ++v) {
                acc[u][v] = fmaf(a[u].x, b[v].x, acc[u][v]);
                acc[u][v] = fmaf(a[u].y, b[v].y, acc[u][v]);
                acc[u][v] = fmaf(a[u].z, b[v].z, acc[u][v]);
                acc[u][v] = fmaf(a[u].w, b[v].w, acc[u][v]);
            }
    }
#pragma unroll
    for (int u = 0; u < 4; ++u) {
        int t = t0 + ty + 16 * u;
#pragma unroll
        for (int v = 0; v < 4; ++v) {
            int i = i0 + tx + 16 * v;
            out[(size_t)t * IN_DIM + i] = acc[u][v] + b_dec[i];
        }
    }
}

// ---------------------------------------------------------------------------
extern "C" void kernel_launch(void* const* d_in, const int* in_sizes, int n_in,
                              void* d_out, int out_size, void* d_ws, size_t ws_size,
                              hipStream_t stream)
{
    const float* x0     = (const float*)d_in[0];
    const float* W_enc  = (const float*)d_in[1];
    const float* b_enc  = (const float*)d_in[2];
    const float* W_ih   = (const float*)d_in[3];
    const float* W_hh   = (const float*)d_in[4];
    const float* bias   = (const float*)d_in[5];
    const float* bias_n = (const float*)d_in[6];
    const float* W_dec  = (const float*)d_in[7];
    const float* b_dec  = (const float*)d_in[8];
    float* out = (float*)d_out;

    // workspace layout (floats): needs ~2.56 MB
    float* ws   = (float*)d_ws;
    float* M    = ws;                 // 16384
    float* cvec = ws + 16384;         // 128
    float* e1   = ws + 16512;         // 128
    float* ig1  = ws + 16640;         // 384
    float* gb   = ws + 17024;         // 768
    float* G    = ws + 17792;         // 98304   (16B-aligned)
    float* H    = ws + 116096;        // 524288  (16B-aligned)

    k_precompute_M<<<128, 128, 0, stream>>>(W_enc, W_dec, b_enc, b_dec, x0, M, cvec, e1);
    k_precompute_G<<<768, 128, 0, stream>>>(W_ih, W_hh, bias, M, cvec, e1, G, gb, ig1);
    k_recurrence<<<1, 1024, 0, stream>>>(G, gb, ig1, bias_n, H);
    dim3 grid(IN_DIM / 64, NSTEPS / 64);
    k_decode<<<grid, 256, 0, stream>>>(H, W_dec, b_dec, out);
}

// Round 8
// 3700.088 us; speedup vs baseline: 1.2957x; 1.2957x over previous
//
#include <hip/hip_runtime.h>
#include <math.h>

#define IN_DIM 8192
#define HID 128
#define NSTEPS 4096

typedef _Float16 f16x8 __attribute__((ext_vector_type(8)));
typedef float f32x4 __attribute__((ext_vector_type(4)));

__device__ __forceinline__ float sigm(float x) { return 1.f / (1.f + __expf(-x)); }
__device__ __forceinline__ float tanh_f(float x) {
    x = fminf(fmaxf(x, -15.f), 15.f);          // avoid inf/inf NaN
    float e = __expf(2.f * x);
    return (e - 1.f) / (e + 1.f);
}

// ---------------------------------------------------------------------------
// Kernel 1: M = W_enc @ W_dec  (128x128), cvec = W_enc@b_dec + b_enc,
//           e1 = W_enc@x0 + b_enc.  Grid: 128 blocks (one per row p), 128 thr.
// ---------------------------------------------------------------------------
__global__ __launch_bounds__(128) void k_precompute_M(
    const float* __restrict__ W_enc, const float* __restrict__ W_dec,
    const float* __restrict__ b_enc, const float* __restrict__ b_dec,
    const float* __restrict__ x0,
    float* __restrict__ M, float* __restrict__ cvec, float* __restrict__ e1)
{
    const int p = blockIdx.x;
    const int t = threadIdx.x;              // 0..127 (= output column q)
    __shared__ float wl[128];
    __shared__ float red[256];
    float m0 = 0.f, m1 = 0.f, m2 = 0.f, m3 = 0.f, cacc = 0.f, eacc = 0.f;
    for (int i0 = 0; i0 < IN_DIM; i0 += 128) {
        float w = W_enc[(size_t)p * IN_DIM + i0 + t];   // coalesced
        cacc = fmaf(w, b_dec[i0 + t], cacc);
        eacc = fmaf(w, x0[i0 + t], eacc);
        wl[t] = w;
        __syncthreads();
#pragma unroll 8
        for (int k = 0; k < 128; k += 4) {              // W_dec reads coalesced in t
            m0 = fmaf(wl[k],     W_dec[(size_t)(i0 + k) * HID + t], m0);
            m1 = fmaf(wl[k + 1], W_dec[(size_t)(i0 + k + 1) * HID + t], m1);
            m2 = fmaf(wl[k + 2], W_dec[(size_t)(i0 + k + 2) * HID + t], m2);
            m3 = fmaf(wl[k + 3], W_dec[(size_t)(i0 + k + 3) * HID + t], m3);
        }
        __syncthreads();
    }
    M[p * HID + t] = (m0 + m1) + (m2 + m3);
    red[t] = cacc; red[128 + t] = eacc;
    __syncthreads();
    for (int s = 64; s > 0; s >>= 1) {
        if (t < s) { red[t] += red[t + s]; red[128 + t] += red[128 + t + s]; }
        __syncthreads();
    }
    if (t == 0) { cvec[p] = red[0] + b_enc[p]; e1[p] = red[128] + b_enc[p]; }
}

// ---------------------------------------------------------------------------
// Kernel 2: G rows 0..383 = W_ih@M, rows 384..767 = W_hh (copy).
//           gb[0..383] = W_ih@cvec + bias, gb[384..767] = 0.
//           ig1 = W_ih@e1 + bias.  Grid: 768 blocks, 128 threads.
// ---------------------------------------------------------------------------
__global__ __launch_bounds__(128) void k_precompute_G(
    const float* __restrict__ W_ih, const float* __restrict__ W_hh,
    const float* __restrict__ bias, const float* __restrict__ M,
    const float* __restrict__ cvec, const float* __restrict__ e1,
    float* __restrict__ G, float* __restrict__ gb, float* __restrict__ ig1)
{
    const int r = blockIdx.x;
    const int q = threadIdx.x;
    if (r >= 384) {
        G[(size_t)r * HID + q] = W_hh[(size_t)(r - 384) * HID + q];
        if (q == 0) gb[r] = 0.f;
        return;
    }
    __shared__ float red[256];
    float a0 = 0.f, a1 = 0.f, a2 = 0.f, a3 = 0.f;
#pragma unroll 8
    for (int k = 0; k < HID; k += 4) {   // W_ih[r][k] scalar-uniform, M coalesced
        a0 = fmaf(W_ih[r * HID + k],     M[(k) * HID + q], a0);
        a1 = fmaf(W_ih[r * HID + k + 1], M[(k + 1) * HID + q], a1);
        a2 = fmaf(W_ih[r * HID + k + 2], M[(k + 2) * HID + q], a2);
        a3 = fmaf(W_ih[r * HID + k + 3], M[(k + 3) * HID + q], a3);
    }
    G[(size_t)r * HID + q] = (a0 + a1) + (a2 + a3);
    float wq = W_ih[r * HID + q];
    red[q] = wq * cvec[q];
    red[128 + q] = wq * e1[q];
    __syncthreads();
    for (int s = 64; s > 0; s >>= 1) {
        if (q < s) { red[q] += red[q + s]; red[128 + q] += red[128 + q + s]; }
        __syncthreads();
    }
    if (q == 0) { gb[r] = red[0] + bias[r]; ig1[r] = red[128] + bias[r]; }
}

// ---------------------------------------------------------------------------
// Kernel 2b: pack G (f32, 768x128 row-major) into MFMA A-fragments (f16).
// Fragment (w,j,c): wave w, tile j (rows 48w+16j..+15), K-chunk c (k=32c..+31).
// A-layout for v_mfma_f32_16x16x32_f16: lane l holds A[row=l&15][k=(l>>4)*8+i].
// Gp[((w*12 + j*4 + c)*64 + l)*8 + i] = G[48w+16j+(l&15)][32c + 8*(l>>4) + i].
// ---------------------------------------------------------------------------
__global__ __launch_bounds__(256) void k_pack(
    const float* __restrict__ G, _Float16* __restrict__ Gp)
{
    int id = blockIdx.x * 256 + threadIdx.x;   // 0..98303
    int i = id & 7;
    int l = (id >> 3) & 63;
    int frag = id >> 9;                        // 0..191 = w*12 + j*4 + c
    int c = frag & 3;
    int j = (frag >> 2) % 3;
    int w = frag / 12;
    int row = 48 * w + 16 * j + (l & 15);
    int k = 32 * c + ((l >> 4) << 3) + i;
    Gp[id] = (_Float16)G[row * HID + k];
}

// ---------------------------------------------------------------------------
// Kernel 3: sequential GRU scan via MFMA. ONE block, 1024 threads (16 waves).
// R1-R7 lesson: VALU paths lose — either weights spill (VGPR heuristic) or
// accvgpr_read chains dominate. MFMA reads AGPRs NATIVELY: weights live as 12
// A-fragments (48 AGPRs/thread, "+a"-pinned), h is broadcast from a 256B LDS
// f16 buffer as the B-operand (value depends only on k -> layout-tolerant;
// internal k-permutations cancel since A and B share the (lane,elem)->k map).
// Per step per wave: 4 ds_read_b128 (B-frags) + 12 MFMA + 3 float4 g-writes.
// D-extract (m89-verified): lane l reg p = g[48w+16j+(l>>4)*4+p]; lanes
// l&15==0 write float4 (+gb). Gates: threads 0..127, h carried in-register.
// ---------------------------------------------------------------------------
#define WF(F) F(0,0) F(0,1) F(0,2) F(0,3) F(1,0) F(1,1) F(1,2) F(1,3) \
              F(2,0) F(2,1) F(2,2) F(2,3)

__global__ __launch_bounds__(1024, 4) void k_recurrence(
    const _Float16* __restrict__ Gp, const float* __restrict__ gb,
    const float* __restrict__ ig1, const float* __restrict__ bias_n,
    float* __restrict__ H)
{
    const int t = threadIdx.x;           // 0..1023
    const int l = t & 63;                // lane
    const int w = t >> 6;                // wave 0..15; rows 48w..48w+47
    __shared__ _Float16 h16[HID];        // 256 B, single copy (broadcast reads)
    __shared__ float g_lds[6 * HID];
    __shared__ float gb_lds[6 * HID];

    if (t < 6 * HID) gb_lds[t] = gb[t];

    // --- stationary weights: 12 MFMA A-fragments -> AGPRs ---
    const f16x8* gpb = (const f16x8*)Gp;
#define DECLW(j,c) f16x8 wf##j##c = gpb[(w * 12 + j * 4 + c) * 64 + l];
    WF(DECLW)
#undef DECLW
#define PINW(j,c) asm volatile("" : "+a"(wf##j##c));
    WF(PINW)
#undef PINW

    const float bnr = (t < HID) ? bias_n[t] : 0.f;
    float hreg = 0.f;

    // step 1: h0 = 0 => hg = 0, use precomputed ig1
    if (t < HID) {
        float ir = ig1[t], iz = ig1[HID + t], inn = ig1[2 * HID + t];
        float rg = sigm(ir), zg = sigm(iz);
        float ng = tanh_f(fmaf(rg, bnr, inn));
        hreg = ng - zg * ng;             // n + z*(0 - n)
        h16[t] = (_Float16)hreg;
        H[t] = hreg;
    }
    __syncthreads();

    const int g4 = l >> 4;                       // 16-lane group 0..3
    const char* hbase = (const char*)h16 + g4 * 16;
    const int pbase = 48 * w + (g4 << 2);        // g-write row base (j=0)
    // folded-bias vectors for this thread's write slots (valid in all lanes)
    const float4 gbv0 = *(const float4*)&gb_lds[pbase];
    const float4 gbv1 = *(const float4*)&gb_lds[pbase + 16];
    const float4 gbv2 = *(const float4*)&gb_lds[pbase + 32];
    const bool writer = (l & 15) == 0;

    for (int st = 1; st < NSTEPS; ++st) {
        // B-fragments: h chunk c, lane l -> h[32c + 8*(l>>4) + i] (16B bcast)
        f16x8 b0 = *(const f16x8*)(hbase);
        f16x8 b1 = *(const f16x8*)(hbase + 64);
        f16x8 b2 = *(const f16x8*)(hbase + 128);
        f16x8 b3 = *(const f16x8*)(hbase + 192);
        f32x4 d0 = {0.f, 0.f, 0.f, 0.f};
        f32x4 d1 = {0.f, 0.f, 0.f, 0.f};
        f32x4 d2 = {0.f, 0.f, 0.f, 0.f};
        d0 = __builtin_amdgcn_mfma_f32_16x16x32_f16(wf00, b0, d0, 0, 0, 0);
        d1 = __builtin_amdgcn_mfma_f32_16x16x32_f16(wf10, b0, d1, 0, 0, 0);
        d2 = __builtin_amdgcn_mfma_f32_16x16x32_f16(wf20, b0, d2, 0, 0, 0);
        d0 = __builtin_amdgcn_mfma_f32_16x16x32_f16(wf01, b1, d0, 0, 0, 0);
        d1 = __builtin_amdgcn_mfma_f32_16x16x32_f16(wf11, b1, d1, 0, 0, 0);
        d2 = __builtin_amdgcn_mfma_f32_16x16x32_f16(wf21, b1, d2, 0, 0, 0);
        d0 = __builtin_amdgcn_mfma_f32_16x16x32_f16(wf02, b2, d0, 0, 0, 0);
        d1 = __builtin_amdgcn_mfma_f32_16x16x32_f16(wf12, b2, d1, 0, 0, 0);
        d2 = __builtin_amdgcn_mfma_f32_16x16x32_f16(wf22, b2, d2, 0, 0, 0);
        d0 = __builtin_amdgcn_mfma_f32_16x16x32_f16(wf03, b3, d0, 0, 0, 0);
        d1 = __builtin_amdgcn_mfma_f32_16x16x32_f16(wf13, b3, d1, 0, 0, 0);
        d2 = __builtin_amdgcn_mfma_f32_16x16x32_f16(wf23, b3, d2, 0, 0, 0);
        if (writer) {                    // lanes 0,16,32,48: rows pbase..+3
            float4 v0 = { d0[0] + gbv0.x, d0[1] + gbv0.y, d0[2] + gbv0.z, d0[3] + gbv0.w };
            float4 v1 = { d1[0] + gbv1.x, d1[1] + gbv1.y, d1[2] + gbv1.z, d1[3] + gbv1.w };
            float4 v2 = { d2[0] + gbv2.x, d2[1] + gbv2.y, d2[2] + gbv2.z, d2[3] + gbv2.w };
            *(float4*)&g_lds[pbase]      = v0;
            *(float4*)&g_lds[pbase + 16] = v1;
            *(float4*)&g_lds[pbase + 32] = v2;
        }
        __syncthreads();
        if (t < HID) {                   // waves 0,1 only; uniform branch
            float ir = g_lds[t],           iz = g_lds[HID + t],     inn = g_lds[2 * HID + t];
            float hr = g_lds[3 * HID + t], hz = g_lds[4 * HID + t], hn = g_lds[5 * HID + t];
            float rg = sigm(ir + hr);
            float zg = sigm(iz + hz);
            float ng = tanh_f(inn + rg * (hn + bnr));
            float hnew = ng + zg * (hreg - ng);
            hreg = hnew;
            h16[t] = (_Float16)hnew;
            H[(size_t)st * HID + t] = hnew;
        }
        __syncthreads();
    }
}

// ---------------------------------------------------------------------------
// Kernel 4: out[t][i] = dot(H[t][:], W_dec[i][:]) + b_dec[i]
// GEMM M=4096(t) N=8192(i) K=128, fp32 vector. 64x64 tiles, 256 threads,
// 4x4 micro-tile (strided by 16), XOR-swizzled LDS (64KB total, conflict-free).
// ---------------------------------------------------------------------------
__global__ __launch_bounds__(256) void k_decode(
    const float* __restrict__ H, const float* __restrict__ W_dec,
    const float* __restrict__ b_dec, float* __restrict__ out)
{
    __shared__ float4 As[64 * 32];   // [t][k4], k4 XOR-swizzled by (t&7)
    __shared__ float4 Bs[64 * 32];   // [i][k4]
    const int tid = threadIdx.x;
    const int t0 = blockIdx.y * 64;
    const int i0 = blockIdx.x * 64;
#pragma unroll 8
    for (int j = 0; j < 8; ++j) {
        int f = tid + 256 * j;        // 0..2047 float4s, coalesced
        int t = f >> 5;
        int k4 = f & 31;
        int sw = k4 ^ (t & 7);
        As[t * 32 + sw] = *(const float4*)(H + (size_t)(t0 + t) * HID + 4 * k4);
        Bs[t * 32 + sw] = *(const float4*)(W_dec + (size_t)(i0 + t) * HID + 4 * k4);
    }
    __syncthreads();
    const int tx = tid & 15, ty = tid >> 4;
    const int xa = ty & 7, xb = tx & 7;
    float acc[4][4] = {{0.f}};
#pragma unroll 8
    for (int k4 = 0; k4 < 32; ++k4) {
        float4 a[4], b[4];
        int ia = k4 ^ xa, ib = k4 ^ xb;
#pragma unroll
        for (int u = 0; u < 4; ++u) a[u] = As[(ty + 16 * u) * 32 + ia];
#pragma unroll
        for (int v = 0; v < 4; ++v) b[v] = Bs[(tx + 16 * v) * 32 + ib];
#pragma unroll
        for (int u = 0; u < 4; ++u)
#pragma unroll
            for (int v = 0; v < 4; ++v) {
                acc[u][v] = fmaf(a[u].x, b[v].x, acc[u][v]);
                acc[u][v] = fmaf(a[u].y, b[v].y, acc[u][v]);
                acc[u][v] = fmaf(a[u].z, b[v].z, acc[u][v]);
                acc[u][v] = fmaf(a[u].w, b[v].w, acc[u][v]);
            }
    }
#pragma unroll
    for (int u = 0; u < 4; ++u) {
        int t = t0 + ty + 16 * u;
#pragma unroll
        for (int v = 0; v < 4; ++v) {
            int i = i0 + tx + 16 * v;
            out[(size_t)t * IN_DIM + i] = acc[u][v] + b_dec[i];
        }
    }
}

// ---------------------------------------------------------------------------
extern "C" void kernel_launch(void* const* d_in, const int* in_sizes, int n_in,
                              void* d_out, int out_size, void* d_ws, size_t ws_size,
                              hipStream_t stream)
{
    const float* x0     = (const float*)d_in[0];
    const float* W_enc  = (const float*)d_in[1];
    const float* b_enc  = (const float*)d_in[2];
    const float* W_ih   = (const float*)d_in[3];
    const float* W_hh   = (const float*)d_in[4];
    const float* bias   = (const float*)d_in[5];
    const float* bias_n = (const float*)d_in[6];
    const float* W_dec  = (const float*)d_in[7];
    const float* b_dec  = (const float*)d_in[8];
    float* out = (float*)d_out;

    // workspace layout (floats): ~2.76 MB
    float* ws   = (float*)d_ws;
    float* M    = ws;                 // 16384
    float* cvec = ws + 16384;         // 128
    float* e1   = ws + 16512;         // 128
    float* ig1  = ws + 16640;         // 384
    float* gb   = ws + 17024;         // 768
    float* G    = ws + 17792;         // 98304   (16B-aligned)
    float* H    = ws + 116096;        // 524288  (16B-aligned)
    _Float16* Gp = (_Float16*)(ws + 640384);   // 98304 f16 (192 KB)

    k_precompute_M<<<128, 128, 0, stream>>>(W_enc, W_dec, b_enc, b_dec, x0, M, cvec, e1);
    k_precompute_G<<<768, 128, 0, stream>>>(W_ih, W_hh, bias, M, cvec, e1, G, gb, ig1);
    k_pack<<<384, 256, 0, stream>>>(G, Gp);
    k_recurrence<<<1, 1024, 0, stream>>>(Gp, gb, ig1, bias_n, H);
    dim3 grid(IN_DIM / 64, NSTEPS / 64);
    k_decode<<<grid, 256, 0, stream>>>(H, W_dec, b_dec, out);
}